// Round 5
// baseline (108.179 us; speedup 1.0000x reference)
//
#include <hip/hip_runtime.h>

// ---------------------------------------------------------------------------
// NeuralTheoremProver depth-1 score, MI355X.  Round 5.
//
//   score[b] = (1/E) * sum_z S1[b,z] * s2[b,z]
//   S1[b,z]  = sum_r sqrt(max(C1[b,r] + Gz[z,r] - 2*hz[b,z], 0))
//   s2[b,z]  = sqrt(max(G2[z] + C2[b] - 2*zt[b,z], 0))
//   hz = H @ E^T, zt = T @ E^T  -> bf16 MFMA 16x16x32
//
// R5 changes vs R4 (R4 post-mortem: main ~37us is epilogue VALU-issue bound,
// ~70 full-rate + 17 trans ops per pair):
//  * fmax(x,0) -> fabs(x): abs is a FREE input modifier on v_sqrt_f32.
//    Numerically safe (differs only for rounding-negative sq, |d|<~1 vs
//    threshold 137; measured absmax was 0.0).
//  * epilogue rewritten in f32x4 vector arithmetic so LLVM emits packed
//    v_pk_fma_f32 / v_pk_add_f32 (gfx90a+): ~24 pk-slots + 16 sqrt per pair
//    vs ~70 + 17 scalar slots.
//  * sq2 via fused fma. Structure (stage-once LDS, 1 barrier, 64z tile,
//    launch_bounds(256,4)) unchanged from R4.
// ---------------------------------------------------------------------------

typedef __attribute__((ext_vector_type(8))) short short8;   // 8 x bf16 (4 VGPR)
typedef __attribute__((ext_vector_type(4))) float f32x4;

__device__ inline unsigned short f2bf(float f) {            // RNE fp32->bf16
  unsigned int u = __float_as_uint(f);
  u += 0x7fffu + ((u >> 16) & 1u);
  return (unsigned short)(u >> 16);
}

// Fused precompute. Block = 256 threads = 16 rows x 16 r-lanes.
// Blocks [0, nEB)   : entity rows  -> Ebf, Gz, G2
// Blocks [nEB, end) : batch rows   -> Hbf, Tbf, C1, C2, out=0
__global__ __launch_bounds__(256) void ntp_pre(
    const float* __restrict__ Etab, const float* __restrict__ rules,
    const int* __restrict__ head, const int* __restrict__ tail,
    const int* __restrict__ qrelp, unsigned short* __restrict__ Ebf,
    unsigned short* __restrict__ Hbf, unsigned short* __restrict__ Tbf,
    float* __restrict__ Gz, float* __restrict__ G2, float* __restrict__ C1,
    float* __restrict__ C2, float* __restrict__ out, int nEB) {
  __shared__ __align__(16) float sR[16][132];   // rules, +4 pad -> 2-way alias
  const int tid = threadIdx.x;
  const int gl = tid >> 4;          // row within this block's 16-row tile
  const int r  = tid & 15;          // rule index
  const int qrel = qrelp[0];

  // Stage all 16 rule rows: 512 f32x4, 2 per thread.
#pragma unroll
  for (int rep = 0; rep < 2; ++rep) {
    int idx = tid + rep * 256;                  // f32x4 index
    int row = idx >> 5, colv = idx & 31;
    *reinterpret_cast<f32x4*>(&sR[row][colv * 4]) =
        *reinterpret_cast<const f32x4*>(rules + (size_t)row * 128 + colv * 4);
  }
  __syncthreads();

  if ((int)blockIdx.x < nEB) {
    const int z = blockIdx.x * 16 + gl;
    const float* ez = Etab + (size_t)z * 128;
    float rz = 0.f, zz = 0.f, rr = 0.f;
#pragma unroll
    for (int k = 0; k < 128; k += 4) {
      f32x4 ev = *reinterpret_cast<const f32x4*>(ez + k);
      f32x4 rv = *reinterpret_cast<const f32x4*>(&sR[r][k]);
#pragma unroll
      for (int j = 0; j < 4; ++j) {
        rz += ev[j] * rv[j];
        zz += ev[j] * ev[j];
        rr += rv[j] * rv[j];
      }
    }
    Gz[(size_t)z * 16 + r] = zz - 2.f * rz;                 // zz - 2 z.r
    if (r == qrel) G2[z] = zz + 2.f * rz + rr;              // zz + 2 z.q + qq
    const float* src = ez + r * 8;
    short8 o;
#pragma unroll
    for (int j = 0; j < 8; ++j) o[j] = (short)f2bf(src[j]);
    *reinterpret_cast<short8*>(Ebf + (size_t)z * 128 + r * 8) = o;
  } else {
    const int b = (blockIdx.x - nEB) * 16 + gl;
    const int hi = head[b], ti = tail[b];
    const float* hp = Etab + (size_t)hi * 128;
    const float* tp = Etab + (size_t)ti * 128;
    float hr = 0.f, tq = 0.f, hh = 0.f, tt = 0.f, rr = 0.f;
#pragma unroll
    for (int k = 0; k < 128; k += 4) {
      f32x4 hv = *reinterpret_cast<const f32x4*>(hp + k);
      f32x4 tv = *reinterpret_cast<const f32x4*>(tp + k);
      f32x4 rv = *reinterpret_cast<const f32x4*>(&sR[r][k]);
#pragma unroll
      for (int j = 0; j < 4; ++j) {
        hr += hv[j] * rv[j];
        tq += tv[j] * rv[j];
        hh += hv[j] * hv[j];
        tt += tv[j] * tv[j];
        rr += rv[j] * rv[j];
      }
    }
    C1[(size_t)b * 16 + r] = hh + rr + 2.f * hr;            // hh + rr + 2 h.r
    if (r == qrel) C2[b] = tt - 2.f * tq;                   // tt - 2 q.t
    if (r == 0) out[b] = 0.f;
    short8 oh, ot;
    const float* hsrc = hp + r * 8;
    const float* tsrc = tp + r * 8;
#pragma unroll
    for (int j = 0; j < 8; ++j) {
      oh[j] = (short)f2bf(hsrc[j]);
      ot[j] = (short)f2bf(tsrc[j]);
    }
    *reinterpret_cast<short8*>(Hbf + (size_t)b * 128 + r * 8) = oh;
    *reinterpret_cast<short8*>(Tbf + (size_t)b * 128 + r * 8) = ot;
  }
}

// Main fused kernel. Block = 32 b x 64 z (2 chunks of 32 z).
// Stage-once to LDS, single barrier, barrier-free compute from LDS.
// 4 waves: wave w -> b-half (w>>1), z-half (w&1); each owns a 16x16 MFMA tile.
// MFMA layouts (m89/m92-verified):
//   A[m=lane&15][k=quad*8+j], B[k=quad*8+j][n=lane&15], D[m=quad*4+reg][n=lane&15]
__global__ __launch_bounds__(256, 4) void ntp_main(
    const unsigned short* __restrict__ Ebf, const unsigned short* __restrict__ Hbf,
    const unsigned short* __restrict__ Tbf, const float* __restrict__ Gz,
    const float* __restrict__ G2, const float* __restrict__ C1,
    const float* __restrict__ C2, float* __restrict__ out, int Ecount) {
  // Pads: sEz row 136 shorts (272B -> 2-way alias = free),
  // sGz/sC1 row 20 f32 (80B -> 2-way; reads are broadcasts anyway).
  __shared__ __align__(16) unsigned short sEz[64][136];   // 17408 B
  __shared__ __align__(16) float sGz[64][20];             //  5120 B
  __shared__ __align__(16) float sG2[64];                 //   256 B
  __shared__ __align__(16) float sC1[32][20];             //  2560 B

  const int tid   = threadIdx.x;
  const int lane  = tid & 63, wave = tid >> 6;
  const int bhalf = wave >> 1, zhalf = wave & 1;
  const int quad  = lane >> 4, lm = lane & 15;
  const int b_base = blockIdx.x * 32;
  const int z_base = blockIdx.y * 64;

  // ---- one-shot staging (coalesced 16B/lane) ----
#pragma unroll
  for (int rep = 0; rep < 4; ++rep) {           // Ez: 64 rows x 256 B
    int c = tid + rep * 256;
    int row = c >> 4, col = c & 15;
    *reinterpret_cast<short8*>(&sEz[row][col * 8]) =
        *reinterpret_cast<const short8*>(Ebf + (size_t)(z_base + row) * 128 + col * 8);
  }
  {                                             // Gz: 64 rows x 64 B
    int row = tid >> 2, colv = tid & 3;
    *reinterpret_cast<f32x4*>(&sGz[row][colv * 4]) =
        *reinterpret_cast<const f32x4*>(Gz + (size_t)(z_base + row) * 16 + colv * 4);
  }
  if (tid < 64) sG2[tid] = G2[z_base + tid];
  if (tid < 128) {                              // C1: 32 rows x 64 B
    int row = tid >> 2, colv = tid & 3;
    *reinterpret_cast<f32x4*>(&sC1[row][colv * 4]) =
        *reinterpret_cast<const f32x4*>(&C1[(size_t)(b_base + row) * 16 + colv * 4]);
  }

  // A-fragments (H and T rows for this wave's 16 b's) register-resident.
  short8 hfrag[4], tfrag[4];
  {
    const size_t brow = (size_t)(b_base + bhalf * 16 + lm) * 128 + quad * 8;
    const unsigned short* hp = Hbf + brow;
    const unsigned short* tp = Tbf + brow;
#pragma unroll
    for (int k4 = 0; k4 < 4; ++k4) {
      hfrag[k4] = *reinterpret_cast<const short8*>(hp + k4 * 32);
      tfrag[k4] = *reinterpret_cast<const short8*>(tp + k4 * 32);
    }
  }

  // C2 for this lane's 4 b's -> registers (independent of lm).
  float c2v[4];
#pragma unroll
  for (int reg = 0; reg < 4; ++reg)
    c2v[reg] = C2[b_base + bhalf * 16 + quad * 4 + reg];

  __syncthreads();   // staging complete; no further barriers.

  const int z_loc = zhalf * 16 + lm;
  const float scale = 1.0f / (float)Ecount;
  f32x4 acc_out = {0.f, 0.f, 0.f, 0.f};

#pragma unroll
  for (int c = 0; c < 2; ++c) {
    const int zr = c * 32 + z_loc;              // LDS row for this lane's z

    f32x4 acc_hz = {0.f, 0.f, 0.f, 0.f};
    f32x4 acc_zt = {0.f, 0.f, 0.f, 0.f};
#pragma unroll
    for (int k4 = 0; k4 < 4; ++k4) {
      short8 ef = *reinterpret_cast<const short8*>(&sEz[zr][k4 * 32 + quad * 8]);
      acc_hz = __builtin_amdgcn_mfma_f32_16x16x32_bf16(hfrag[k4], ef, acc_hz, 0, 0, 0);
      acc_zt = __builtin_amdgcn_mfma_f32_16x16x32_bf16(tfrag[k4], ef, acc_zt, 0, 0, 0);
    }

    f32x4 gr[4];
#pragma unroll
    for (int i = 0; i < 4; ++i)
      gr[i] = *reinterpret_cast<const f32x4*>(&sGz[zr][i * 4]);
    const float g2v = sG2[zr];

#pragma unroll
    for (int reg = 0; reg < 4; ++reg) {
      const int b_loc = bhalf * 16 + quad * 4 + reg;
      const float hz = acc_hz[reg], zt = acc_zt[reg];
      // s2 = sqrt(|g2 + c2 - 2 zt|)  (abs: free sqrt input modifier)
      const float s2 = __builtin_amdgcn_sqrtf(
          __builtin_fabsf(__builtin_fmaf(-2.f, zt, g2v + c2v[reg])));
      // S1 = sum_r sqrt(|c1[r] + gr[r] - 2 hz|), vectorized f32x4 so the
      // backend emits v_pk_fma_f32 / v_pk_add_f32 (2 fp32 lanes per slot).
      const f32x4 hz4 = {hz, hz, hz, hz};
      const f32x4 mtwo = {-2.f, -2.f, -2.f, -2.f};
      f32x4 s1v = {0.f, 0.f, 0.f, 0.f};
#pragma unroll
      for (int i = 0; i < 4; ++i) {
        f32x4 c1v = *reinterpret_cast<const f32x4*>(&sC1[b_loc][i * 4]);  // bcast
        f32x4 sq = (hz4 * mtwo + gr[i]) + c1v;   // pk-fma + pk-add
        f32x4 rt;
#pragma unroll
        for (int j = 0; j < 4; ++j)
          rt[j] = __builtin_amdgcn_sqrtf(__builtin_fabsf(sq[j]));
        s1v += rt;                               // pk-add
      }
      const float S1 = (s1v[0] + s1v[1]) + (s1v[2] + s1v[3]);
      acc_out[reg] = __builtin_fmaf(S1, s2, acc_out[reg]);  // (-S1)(-s2)=S1*s2
    }
  }

  // Reduce over the 16 n-lanes, then one atomic per (b, z-block).
#pragma unroll
  for (int reg = 0; reg < 4; ++reg) {
    float v = acc_out[reg];
    v += __shfl_xor(v, 1, 16);
    v += __shfl_xor(v, 2, 16);
    v += __shfl_xor(v, 4, 16);
    v += __shfl_xor(v, 8, 16);
    if (lm == 0)
      atomicAdd(&out[b_base + bhalf * 16 + quad * 4 + reg], v * scale);
  }
}

extern "C" void kernel_launch(void* const* d_in, const int* in_sizes, int n_in,
                              void* d_out, int out_size, void* d_ws, size_t ws_size,
                              hipStream_t stream) {
  const int* head  = (const int*)d_in[0];
  const int* tail  = (const int*)d_in[1];
  const int* qrel  = (const int*)d_in[2];
  // d_in[3] = depth (unused at depth==1 closed form)
  const float* Etab  = (const float*)d_in[4];
  const float* rules = (const float*)d_in[5];
  const int B = in_sizes[0];
  const int E = in_sizes[4] / 128;
  float* out = (float*)d_out;

  char* ws = (char*)d_ws;
  unsigned short* Ebf = (unsigned short*)ws;                       // E*128*2 B
  unsigned short* Hbf = (unsigned short*)(ws + (size_t)E * 256);   // B*128*2 B
  unsigned short* Tbf = Hbf + (size_t)B * 128;                     // B*128*2 B
  float* Gz = (float*)(ws + (size_t)E * 256 + (size_t)B * 512);    // E*16*4 B
  float* G2 = Gz + (size_t)E * 16;                                 // E*4 B
  float* C1 = G2 + E;                                              // B*16*4 B
  float* C2 = C1 + (size_t)B * 16;                                 // B*4 B

  const int nEB = E / 16;                                          // 512
  const int nBB = B / 16;                                          // 64
  ntp_pre<<<nEB + nBB, 256, 0, stream>>>(Etab, rules, head, tail, qrel, Ebf,
                                         Hbf, Tbf, Gz, G2, C1, C2, out, nEB);
  ntp_main<<<dim3(B / 32, E / 64), 256, 0, stream>>>(Ebf, Hbf, Tbf, Gz, G2, C1,
                                                     C2, out, E);
}